// Round 1
// baseline (232.957 us; speedup 1.0000x reference)
//
#include <hip/hip_runtime.h>
#include <hip/hip_bf16.h>

// CapsNet dynamic routing, algebraically refactored so pred[b,i,j,d] is never
// materialized:
//   y[b,j,c] = sum_i c[b,j,i] x[b,c,i]          (K1, MFMA fp16)
//   s[b,j,d] = sum_c W2[j,d,c] y[b,j,c] + bias[j,d]*csum[b,j]   (K2)
//   v = squash(s); u[b,j,c] = sum_d v W2[j,d,c]; vb = v.bias    (K2)
//   b += u @ x + vb                              (K3, MFMA fp16)
// 3 iterations; last iteration stops at v (written to d_out).

#define BSZ 256
#define CDIM 256
#define IDIM 256
#define JDIM 32
#define DDIM 64

typedef _Float16 f16x8 __attribute__((ext_vector_type(8)));
typedef float f32x4 __attribute__((ext_vector_type(4)));

// ---------------------------------------------------------------------------
// K1: softmax over j (per column i) + y[j,c'] = sum_i c[j,i]*x[c',i]
// grid (BSZ, 2) : blockIdx.y selects c'-half. block 256.
// ---------------------------------------------------------------------------
__global__ __launch_bounds__(256) void k1_softmax_y(
    const float* __restrict__ x,      // [BSZ][CDIM][IDIM]
    const float* __restrict__ bsrc,   // [BSZ][JDIM][IDIM]
    float* __restrict__ y_ws,         // [BSZ][JDIM][CDIM]
    float* __restrict__ csum_ws)      // [BSZ][JDIM]
{
  __shared__ __align__(16) _Float16 cs[JDIM * 264];  // c[j][i], padded rows
  const int b = blockIdx.x;
  const int t = threadIdx.x;

  // softmax over j for column i = t (fully in registers)
  {
    const float* bp = bsrc + (size_t)b * (JDIM * IDIM) + t;
    float bv[JDIM];
    #pragma unroll
    for (int j = 0; j < JDIM; ++j) bv[j] = bp[j * IDIM];
    float m = bv[0];
    #pragma unroll
    for (int j = 1; j < JDIM; ++j) m = fmaxf(m, bv[j]);
    float s = 0.f;
    #pragma unroll
    for (int j = 0; j < JDIM; ++j) { bv[j] = __expf(bv[j] - m); s += bv[j]; }
    float r = 1.f / s;
    #pragma unroll
    for (int j = 0; j < JDIM; ++j) cs[j * 264 + t] = (_Float16)(bv[j] * r);
  }
  __syncthreads();

  // csum[j] = sum_i c[j][i]  (only one grid-y half writes it)
  if (blockIdx.y == 0 && t < JDIM) {
    float su = 0.f;
    for (int i = 0; i < IDIM; ++i) su += (float)cs[t * 264 + i];
    csum_ws[b * JDIM + t] = su;
  }

  const int w = t >> 6, lane = t & 63, l15 = lane & 15, quad = lane >> 4;
  const int cbase = blockIdx.y * 128 + w * 32;
  const float* xb = x + (size_t)b * (CDIM * IDIM);

  f32x4 acc[2][2];
  #pragma unroll
  for (int mt = 0; mt < 2; ++mt)
    #pragma unroll
    for (int nt = 0; nt < 2; ++nt)
      acc[mt][nt] = (f32x4){0.f, 0.f, 0.f, 0.f};

  for (int k0 = 0; k0 < IDIM; k0 += 32) {
    const int ko = k0 + quad * 8;
    f16x8 a0 = *reinterpret_cast<const f16x8*>(&cs[l15 * 264 + ko]);
    f16x8 a1 = *reinterpret_cast<const f16x8*>(&cs[(16 + l15) * 264 + ko]);
    #pragma unroll
    for (int nt = 0; nt < 2; ++nt) {
      const int cp = cbase + nt * 16 + l15;
      const float* xp = xb + cp * IDIM + ko;  // contiguous in i (=k): clean
      float4 p0 = *reinterpret_cast<const float4*>(xp);
      float4 p1 = *reinterpret_cast<const float4*>(xp + 4);
      f16x8 bf;
      bf[0] = (_Float16)p0.x; bf[1] = (_Float16)p0.y;
      bf[2] = (_Float16)p0.z; bf[3] = (_Float16)p0.w;
      bf[4] = (_Float16)p1.x; bf[5] = (_Float16)p1.y;
      bf[6] = (_Float16)p1.z; bf[7] = (_Float16)p1.w;
      acc[0][nt] = __builtin_amdgcn_mfma_f32_16x16x32_f16(a0, bf, acc[0][nt], 0, 0, 0);
      acc[1][nt] = __builtin_amdgcn_mfma_f32_16x16x32_f16(a1, bf, acc[1][nt], 0, 0, 0);
    }
  }

  float* yb = y_ws + (size_t)b * (JDIM * CDIM);
  #pragma unroll
  for (int mt = 0; mt < 2; ++mt)
    #pragma unroll
    for (int nt = 0; nt < 2; ++nt) {
      const int cp = cbase + nt * 16 + l15;
      #pragma unroll
      for (int rr = 0; rr < 4; ++rr) {
        const int j = mt * 16 + quad * 4 + rr;
        yb[j * CDIM + cp] = acc[mt][nt][rr];
      }
    }
}

// ---------------------------------------------------------------------------
// K2: s = W_j . y + bias*csum ; v = squash(s) ; u = v^T W_j ; vb = v.bias
// grid 1024 = 32 j * 32 chunks of 8 batches. block 256.
// W_j staged in LDS once, reused for 8 batches.
// ---------------------------------------------------------------------------
__global__ __launch_bounds__(256) void k2_route(
    const float* __restrict__ W,       // [JDIM*DDIM][CDIM]
    const float* __restrict__ bias,    // [JDIM*DDIM]
    const float* __restrict__ y_ws,    // [BSZ][JDIM][CDIM]
    const float* __restrict__ csum_ws, // [BSZ][JDIM]
    _Float16* __restrict__ u16,        // [BSZ][JDIM][CDIM]   (mid only)
    float* __restrict__ vb_ws,         // [BSZ][JDIM]         (mid only)
    float* __restrict__ vout,          // [BSZ][JDIM][DDIM]   (final only)
    int final_iter)
{
  __shared__ __align__(16) float Wj[DDIM * 260];
  __shared__ __align__(16) float ysh[8 * 256];
  __shared__ __align__(16) float vsh[8 * 64];
  __shared__ float bjs[DDIM];
  __shared__ float csums[8];
  const int jb = blockIdx.x & 31;
  const int b0 = (blockIdx.x >> 5) * 8;
  const int t = threadIdx.x;

  // stage W_j (64x256 fp32) as float4, padded stride 260
  for (int p = t; p < DDIM * 64; p += 256) {
    int d = p >> 6, cq = p & 63;
    *reinterpret_cast<float4*>(&Wj[d * 260 + cq * 4]) =
        *reinterpret_cast<const float4*>(&W[(size_t)(jb * DDIM + d) * CDIM + cq * 4]);
  }
  // stage y rows for the 8 batches
  for (int p = t; p < 8 * 64; p += 256) {
    int bs_ = p >> 6, cq = p & 63;
    *reinterpret_cast<float4*>(&ysh[bs_ * 256 + cq * 4]) =
        *reinterpret_cast<const float4*>(&y_ws[((size_t)(b0 + bs_) * JDIM + jb) * CDIM + cq * 4]);
  }
  if (t < DDIM) bjs[t] = bias[jb * DDIM + t];
  if (t < 8)    csums[t] = csum_ws[(b0 + t) * JDIM + jb];
  __syncthreads();

  const int bs = t >> 5;   // batch within chunk (0..7)
  const int dd = t & 31;   // handles d = dd and d = dd+32
  float s0 = 0.f, s1 = 0.f;
  const float* yr  = &ysh[bs * 256];
  const float* w0p = &Wj[dd * 260];
  const float* w1p = &Wj[(dd + 32) * 260];
  for (int c = 0; c < CDIM; c += 4) {
    float4 yv = *reinterpret_cast<const float4*>(&yr[c]);
    float4 wa = *reinterpret_cast<const float4*>(&w0p[c]);
    float4 wb = *reinterpret_cast<const float4*>(&w1p[c]);
    s0 += yv.x * wa.x + yv.y * wa.y + yv.z * wa.z + yv.w * wa.w;
    s1 += yv.x * wb.x + yv.y * wb.y + yv.z * wb.z + yv.w * wb.w;
  }
  float cz = csums[bs];
  s0 += bjs[dd] * cz;
  s1 += bjs[dd + 32] * cz;

  // squash: ||s||^2 over the 32 lanes of this half-wave (2 d's per lane)
  float n2 = s0 * s0 + s1 * s1;
  n2 += __shfl_xor(n2, 16, 32);
  n2 += __shfl_xor(n2, 8, 32);
  n2 += __shfl_xor(n2, 4, 32);
  n2 += __shfl_xor(n2, 2, 32);
  n2 += __shfl_xor(n2, 1, 32);
  float nrm = sqrtf(n2);
  float sc = nrm / (1.f + n2);     // v = s * n/(1+n^2), safe at n=0
  float v0 = s0 * sc, v1 = s1 * sc;

  if (final_iter) {
    float* vp = vout + ((size_t)(b0 + bs) * JDIM + jb) * DDIM;
    vp[dd] = v0;
    vp[dd + 32] = v1;
  } else {
    vsh[bs * 64 + dd] = v0;
    vsh[bs * 64 + dd + 32] = v1;
    float vb = v0 * bjs[dd] + v1 * bjs[dd + 32];
    vb += __shfl_xor(vb, 16, 32);
    vb += __shfl_xor(vb, 8, 32);
    vb += __shfl_xor(vb, 4, 32);
    vb += __shfl_xor(vb, 2, 32);
    vb += __shfl_xor(vb, 1, 32);
    if (dd == 0) vb_ws[(b0 + bs) * JDIM + jb] = vb;
    __syncthreads();

    // u[bs][c=t] = sum_d v[bs][d] * Wj[d][c], all 8 batches per thread
    float ua[8] = {0.f, 0.f, 0.f, 0.f, 0.f, 0.f, 0.f, 0.f};
    for (int d0 = 0; d0 < DDIM; d0 += 4) {
      float q0 = Wj[(d0 + 0) * 260 + t];
      float q1 = Wj[(d0 + 1) * 260 + t];
      float q2 = Wj[(d0 + 2) * 260 + t];
      float q3 = Wj[(d0 + 3) * 260 + t];
      #pragma unroll
      for (int k = 0; k < 8; ++k) {
        float4 vv = *reinterpret_cast<const float4*>(&vsh[k * 64 + d0]);
        ua[k] += vv.x * q0 + vv.y * q1 + vv.z * q2 + vv.w * q3;
      }
    }
    #pragma unroll
    for (int k = 0; k < 8; ++k)
      u16[((size_t)(b0 + k) * JDIM + jb) * CDIM + t] = (_Float16)ua[k];
  }
}

// ---------------------------------------------------------------------------
// K3: b_new[j,i] = b_old[j,i] + sum_c u[j,c]*x[c,i] + vb[j]
// grid (BSZ, 2) : blockIdx.y selects i-half. block 256.
// ---------------------------------------------------------------------------
__global__ __launch_bounds__(256) void k3_delta(
    const float* __restrict__ x,       // [BSZ][CDIM][IDIM]
    const _Float16* __restrict__ u16,  // [BSZ][JDIM][CDIM]
    const float* __restrict__ vb_ws,   // [BSZ][JDIM]
    const float* __restrict__ bsrc,    // [BSZ][JDIM][IDIM]
    float* __restrict__ bdst)          // [BSZ][JDIM][IDIM]
{
  __shared__ __align__(16) _Float16 us[JDIM * 264];
  __shared__ float vbs[JDIM];
  const int b = blockIdx.x;
  const int t = threadIdx.x;

  const int* ug = reinterpret_cast<const int*>(u16 + (size_t)b * (JDIM * CDIM));
  for (int p = t; p < 4096; p += 256) {   // 8192 halves as 4096 ints
    int j = p >> 7, c2 = p & 127;
    *reinterpret_cast<int*>(&us[j * 264 + c2 * 2]) = ug[p];
  }
  if (t < JDIM) vbs[t] = vb_ws[b * JDIM + t];
  __syncthreads();

  const int w = t >> 6, lane = t & 63, l15 = lane & 15, quad = lane >> 4;
  const int ibase = blockIdx.y * 128 + w * 32;
  const float* xb = x + (size_t)b * (CDIM * IDIM);

  f32x4 acc[2][2];
  #pragma unroll
  for (int mt = 0; mt < 2; ++mt)
    #pragma unroll
    for (int nt = 0; nt < 2; ++nt)
      acc[mt][nt] = (f32x4){0.f, 0.f, 0.f, 0.f};

  for (int k0 = 0; k0 < CDIM; k0 += 32) {
    const int ko = k0 + quad * 8;
    f16x8 a0 = *reinterpret_cast<const f16x8*>(&us[l15 * 264 + ko]);
    f16x8 a1 = *reinterpret_cast<const f16x8*>(&us[(16 + l15) * 264 + ko]);
    #pragma unroll
    for (int nt = 0; nt < 2; ++nt) {
      const int ii = ibase + nt * 16 + l15;
      const float* xp = xb + (size_t)ko * IDIM + ii;  // k=c is strided: 8 scalars
      f16x8 bf;
      #pragma unroll
      for (int ss = 0; ss < 8; ++ss)
        bf[ss] = (_Float16)xp[ss * IDIM];
      acc[0][nt] = __builtin_amdgcn_mfma_f32_16x16x32_f16(a0, bf, acc[0][nt], 0, 0, 0);
      acc[1][nt] = __builtin_amdgcn_mfma_f32_16x16x32_f16(a1, bf, acc[1][nt], 0, 0, 0);
    }
  }

  const float* bsb = bsrc + (size_t)b * (JDIM * IDIM);
  float* bdb = bdst + (size_t)b * (JDIM * IDIM);
  #pragma unroll
  for (int mt = 0; mt < 2; ++mt)
    #pragma unroll
    for (int nt = 0; nt < 2; ++nt) {
      const int ii = ibase + nt * 16 + l15;
      #pragma unroll
      for (int rr = 0; rr < 4; ++rr) {
        const int j = mt * 16 + quad * 4 + rr;
        const int idx = j * IDIM + ii;
        bdb[idx] = bsb[idx] + acc[mt][nt][rr] + vbs[j];
      }
    }
}

// ---------------------------------------------------------------------------
extern "C" void kernel_launch(void* const* d_in, const int* in_sizes, int n_in,
                              void* d_out, int out_size, void* d_ws, size_t ws_size,
                              hipStream_t stream) {
  (void)in_sizes; (void)n_in; (void)out_size; (void)ws_size;
  const float* x      = (const float*)d_in[0];
  const float* W      = (const float*)d_in[1];
  const float* bias   = (const float*)d_in[2];
  const float* b_init = (const float*)d_in[3];
  char* ws = (char*)d_ws;

  float*    y_ws    = (float*)(ws);                              // 8 MB
  _Float16* u16     = (_Float16*)(ws + (8u << 20));              // 4 MB
  float*    b_ws    = (float*)(ws + (12u << 20));                // 8 MB
  float*    csum_ws = (float*)(ws + (20u << 20));                // 32 KB
  float*    vb_ws   = (float*)(ws + (20u << 20) + (32u << 10));  // 32 KB
  float*    vout    = (float*)d_out;

  dim3 g12(BSZ, 2);

  // iter 1
  k1_softmax_y<<<g12, 256, 0, stream>>>(x, b_init, y_ws, csum_ws);
  k2_route<<<1024, 256, 0, stream>>>(W, bias, y_ws, csum_ws, u16, vb_ws, vout, 0);
  k3_delta<<<g12, 256, 0, stream>>>(x, u16, vb_ws, b_init, b_ws);
  // iter 2
  k1_softmax_y<<<g12, 256, 0, stream>>>(x, b_ws, y_ws, csum_ws);
  k2_route<<<1024, 256, 0, stream>>>(W, bias, y_ws, csum_ws, u16, vb_ws, vout, 0);
  k3_delta<<<g12, 256, 0, stream>>>(x, u16, vb_ws, b_ws, b_ws);
  // iter 3 (only need v)
  k1_softmax_y<<<g12, 256, 0, stream>>>(x, b_ws, y_ws, csum_ws);
  k2_route<<<1024, 256, 0, stream>>>(W, bias, y_ws, csum_ws, u16, vb_ws, vout, 1);
}